// Round 14
// baseline (425.576 us; speedup 1.0000x reference)
//
#include <hip/hip_runtime.h>
#include <hip/hip_bf16.h>

typedef unsigned short u16;
typedef __attribute__((ext_vector_type(8))) short short8;   // 8 bf16 = 4 VGPR
typedef __attribute__((ext_vector_type(4))) float f32x4;

#define MAXC 256
#define REPS 16

__device__ __forceinline__ float b2f(u16 b) {
    return __uint_as_float(((unsigned)b) << 16);
}
// fp32 -> bf16 RNE
__device__ __forceinline__ u16 f2b(float f) {
    unsigned u = __float_as_uint(f);
    return (u16)((u + 0x7FFFu + ((u >> 16) & 1u)) >> 16);
}
__device__ __forceinline__ uint2 cvt4(float4 f) {
    uint2 r;
    r.x = (unsigned)f2b(f.x) | ((unsigned)f2b(f.y) << 16);
    r.y = (unsigned)f2b(f.z) | ((unsigned)f2b(f.w) << 16);
    return r;
}

// ===========================================================================
// MEASUREMENT ROUND: each kernel repeats its body REPS(16)x internally
// (byte-identical rewrites / idempotent atomics -> output unchanged).
// Each kernel's dispatch duration then exceeds the 42us harness fills and
// appears in the rocprof top-5: per-kernel time = dur/16. The
// asm-memory-clobber per rep prevents load hoisting, so memory traffic is
// genuinely repeated.
// ===========================================================================

// ---------------------------------------------------------------------------
// K1 prep, 5 parallel roles.
// ---------------------------------------------------------------------------
__global__ __launch_bounds__(256) void prep_kernel(
    const int* __restrict__ e, int E,
    uint4* __restrict__ maskv, int mask16, unsigned* __restrict__ orbuf,
    const float* __restrict__ Wp, u16* __restrict__ wpb,
    const float* __restrict__ x,  u16* __restrict__ xb,
    const float* __restrict__ Wq, const float* __restrict__ Wk,
    const float* __restrict__ Wv, u16* __restrict__ wqkvb, int reps)
{
    int b = blockIdx.x, t = threadIdx.x;
    for (int rep = 0; rep < reps; rep++) {
        if (b < 192) {
            uint4 z = {0u, 0u, 0u, 0u};
            for (int i = b * 256 + t; i < mask16; i += 192 * 256) maskv[i] = z;
        } else if (b < 256) {
            int bb = b - 192;
            unsigned acc = 0;
            for (int i = bb * 256 + t; i < E; i += 64 * 256)
                acc |= (unsigned)e[2 * i + 1];
            __shared__ unsigned red[4];
            #pragma unroll
            for (int o = 32; o > 0; o >>= 1) acc |= __shfl_xor(acc, o, 64);
            if ((t & 63) == 0) red[t >> 6] = acc;
            __syncthreads();
            if (t == 0) orbuf[bb] = red[0] | red[1] | red[2] | red[3];
            __syncthreads();              // protect red before next rep
        } else if (b < 384) {
            int i = (b - 256) * 256 + t;
            *(uint2*)(wpb + 4 * (size_t)i) = cvt4(((const float4*)Wp)[i]);
        } else if (b < 640) {
            int base = (b - 384) * 1024;
            #pragma unroll
            for (int r = 0; r < 4; r++) {
                int i = base + r * 256 + t;
                *(uint2*)(xb + 4 * (size_t)i) = cvt4(((const float4*)x)[i]);
            }
        } else {
            int base = (b - 640) * 1024;
            #pragma unroll
            for (int r = 0; r < 4; r++) {
                int i = base + r * 256 + t;
                float4 f;
                if (i < 16384)      f = ((const float4*)Wq)[i];
                else if (i < 32768) f = ((const float4*)Wk)[i - 16384];
                else                f = ((const float4*)Wv)[i - 32768];
                *(uint2*)(wqkvb + 4 * (size_t)i) = cvt4(f);
            }
        }
        asm volatile("" ::: "memory");
    }
}

// ---------------------------------------------------------------------------
// K2 fused scatter + QKV MFMA GEMM.
// ---------------------------------------------------------------------------
__global__ __launch_bounds__(256) void scatter_qkv_kernel(
    const int* __restrict__ e, int E, int N,
    unsigned* __restrict__ mask, const unsigned* __restrict__ orbuf,
    const u16* __restrict__ xb, const u16* __restrict__ wqkvb,
    const float* __restrict__ bq, const float* __restrict__ bk,
    const float* __restrict__ bv,
    u16* __restrict__ q, u16* __restrict__ k, u16* __restrict__ v, int reps)
{
    int t = threadIdx.x;

    if (blockIdx.x < 128) {
        unsigned oo = orbuf[t & 63];
        #pragma unroll
        for (int o = 32; o > 0; o >>= 1) oo |= __shfl_xor(oo, o, 64);
        bool i32mode = (oo != 0);
        int nw = N >> 5;
        for (int rep = 0; rep < reps; rep++) {
            for (int i = blockIdx.x * 256 + t; i < E; i += 128 * 256) {
                int row, col;
                if (i32mode) { row = e[i];     col = e[E + i]; }
                else         { row = e[2 * i]; col = e[2 * E + 2 * i]; }
                if ((unsigned)row < (unsigned)N && (unsigned)col < (unsigned)N)
                    atomicOr(&mask[(size_t)row * nw + (col >> 5)], 1u << (col & 31));
            }
            asm volatile("" ::: "memory");
        }
        return;
    }

    int bid = blockIdx.x - 128;
    int bx = bid & 31, by = bid >> 5;
    int which = by >> 2;
    int ncl = (by & 3) * 64;
    int n0f = which * 256 + ncl;
    const float* bias = (which == 0) ? bq : (which == 1) ? bk : bv;
    u16*         T    = (which == 0) ? q  : (which == 1) ? k  : v;

    int wv = t >> 6, l = t & 63, lr = l & 15, lk = l >> 4;
    int m0 = bx * 128 + wv * 32;
    const short8* a0p = (const short8*)(xb + (size_t)(m0 + lr) * 256 + lk * 8);
    const short8* a1p = (const short8*)(xb + (size_t)(m0 + 16 + lr) * 256 + lk * 8);
    const short8* wp_ = (const short8*)(wqkvb + (size_t)(n0f + lr) * 256 + lk * 8);

    for (int rep = 0; rep < reps; rep++) {
        f32x4 acc[2][4] = {};
        #pragma unroll
        for (int kk = 0; kk < 8; kk++) {
            short8 a0 = a0p[kk * 4];
            short8 a1 = a1p[kk * 4];
            #pragma unroll
            for (int j = 0; j < 4; j++) {
                short8 b = wp_[(size_t)j * 16 * 32 + kk * 4];
                acc[0][j] = __builtin_amdgcn_mfma_f32_16x16x32_bf16(a0, b, acc[0][j], 0, 0, 0);
                acc[1][j] = __builtin_amdgcn_mfma_f32_16x16x32_bf16(a1, b, acc[1][j], 0, 0, 0);
            }
        }
        #pragma unroll
        for (int i2 = 0; i2 < 2; i2++)
            #pragma unroll
            for (int j = 0; j < 4; j++)
                #pragma unroll
                for (int r = 0; r < 4; r++) {
                    int grow = m0 + i2 * 16 + lk * 4 + r;
                    int gc   = ncl + j * 16 + lr;
                    T[(size_t)grow * 256 + gc] = f2b(acc[i2][j][r] + bias[gc]);
                }
        asm volatile("" ::: "memory");
    }
}

// ---------------------------------------------------------------------------
// K3 attn: one row per wave (unchanged math).
// ---------------------------------------------------------------------------
__global__ __launch_bounds__(256) void attn_kernel(
    const unsigned* __restrict__ mask,
    const u16* __restrict__ qb, const u16* __restrict__ kb,
    const u16* __restrict__ vb, u16* __restrict__ yb, int N, int reps)
{
    __shared__ int   cols[4][MAXC];
    __shared__ float ws[4][8][16];
    __shared__ float fs[4][8];
    __shared__ float lsums[4][8];

    int t = threadIdx.x;
    int wv = t >> 6, lane = t & 63;
    int n = blockIdx.x * 4 + wv;
    int nw = N >> 5;

    for (int rep = 0; rep < reps; rep++) {
        unsigned wa = mask[(size_t)n * nw + lane];
        unsigned wb = mask[(size_t)n * nw + 64 + lane];
        int pc = __popc(wa) + __popc(wb);
        int scan = pc;
        #pragma unroll
        for (int o = 1; o < 64; o <<= 1) {
            int pv = __shfl_up(scan, o, 64);
            if (lane >= o) scan += pv;
        }
        int cnt = __shfl(scan, 63, 64);
        if (cnt > MAXC) cnt = MAXC;
        int off = scan - pc;
        while (wa && off < MAXC) {
            int b = __ffs(wa) - 1; wa &= wa - 1;
            cols[wv][off++] = (lane << 5) + b;
        }
        while (wb && off < MAXC) {
            int b = __ffs(wb) - 1; wb &= wb - 1;
            cols[wv][off++] = ((64 + lane) << 5) + b;
        }
        int cntp = (cnt + 15) & ~15;
        if (cntp > MAXC) cntp = MAXC;
        for (int i = cnt + lane; i < cntp; i += 64) cols[wv][i] = n;
        asm volatile("s_waitcnt lgkmcnt(0)" ::: "memory");

        int h8 = lane >> 4;
        int jl = lane & 15;
        int hv = lane >> 3;
        int d0 = lane * 4;

        const short8* qpA = (const short8*)(qb + (size_t)n * 256 + h8 * 32);
        const short8* qpB = (const short8*)(qb + (size_t)n * 256 + (h8 + 4) * 32);
        short8 qA0 = qpA[0], qA1 = qpA[1];
        short8 qB0 = qpB[0], qB1 = qpB[1];

        const float scale = 0.17677669529663687f;
        float mxA = -1e30f, mxB = -1e30f, lsA = 0.f, lsB = 0.f;
        float acc0 = 0.f, acc1 = 0.f, acc2 = 0.f, acc3 = 0.f;

        for (int c0 = 0; c0 < cnt; c0 += 16) {
            bool valid = (c0 + jl) < cnt;
            const u16* kr = kb + (size_t)cols[wv][c0 + jl] * 256;
            short8 a0 = ((const short8*)(kr + h8 * 32))[0];
            short8 a1 = ((const short8*)(kr + h8 * 32))[1];
            short8 b0 = ((const short8*)(kr + (h8 + 4) * 32))[0];
            short8 b1 = ((const short8*)(kr + (h8 + 4) * 32))[1];
            float sa = 0.f, sb = 0.f;
            #pragma unroll
            for (int e2 = 0; e2 < 8; e2++) {
                sa = fmaf(b2f((u16)a0[e2]), b2f((u16)qA0[e2]), sa);
                sa = fmaf(b2f((u16)a1[e2]), b2f((u16)qA1[e2]), sa);
                sb = fmaf(b2f((u16)b0[e2]), b2f((u16)qB0[e2]), sb);
                sb = fmaf(b2f((u16)b1[e2]), b2f((u16)qB1[e2]), sb);
            }
            float s0 = valid ? sa * scale : -1e30f;
            float s1 = valid ? sb * scale : -1e30f;

            float cm0 = s0, cm1 = s1;
            #pragma unroll
            for (int o = 8; o > 0; o >>= 1) {
                cm0 = fmaxf(cm0, __shfl_xor(cm0, o, 16));
                cm1 = fmaxf(cm1, __shfl_xor(cm1, o, 16));
            }
            float mnA = fmaxf(mxA, cm0), mnB = fmaxf(mxB, cm1);
            float fA = __expf(mxA - mnA), fB = __expf(mxB - mnB);
            float w0 = valid ? __expf(s0 - mnA) : 0.f;
            float w1 = valid ? __expf(s1 - mnB) : 0.f;
            float t0 = w0, t1 = w1;
            #pragma unroll
            for (int o = 8; o > 0; o >>= 1) {
                t0 += __shfl_xor(t0, o, 16);
                t1 += __shfl_xor(t1, o, 16);
            }
            lsA = lsA * fA + t0;  lsB = lsB * fB + t1;
            mxA = mnA;            mxB = mnB;

            ws[wv][h8][jl]     = w0;
            ws[wv][h8 + 4][jl] = w1;
            if (jl == 0) { fs[wv][h8] = fA; fs[wv][h8 + 4] = fB; }
            asm volatile("s_waitcnt lgkmcnt(0)" ::: "memory");

            float fv = fs[wv][hv];
            acc0 *= fv; acc1 *= fv; acc2 *= fv; acc3 *= fv;
            #pragma unroll
            for (int j = 0; j < 16; j++) {
                float wj = ws[wv][hv][j];
                uint2 raw = *(const uint2*)(vb + (size_t)cols[wv][c0 + j] * 256 + d0);
                acc0 = fmaf(wj, b2f((u16)(raw.x & 0xffff)), acc0);
                acc1 = fmaf(wj, b2f((u16)(raw.x >> 16)),    acc1);
                acc2 = fmaf(wj, b2f((u16)(raw.y & 0xffff)), acc2);
                acc3 = fmaf(wj, b2f((u16)(raw.y >> 16)),    acc3);
            }
        }

        if (jl == 0) { lsums[wv][h8] = lsA; lsums[wv][h8 + 4] = lsB; }
        asm volatile("s_waitcnt lgkmcnt(0)" ::: "memory");
        float ls = lsums[wv][hv];
        uint2 ov;
        if (cnt > 0) {
            ov.x = (unsigned)f2b(acc0 / ls) | ((unsigned)f2b(acc1 / ls) << 16);
            ov.y = (unsigned)f2b(acc2 / ls) | ((unsigned)f2b(acc3 / ls) << 16);
        } else {
            ov.x = 0u; ov.y = 0u;
        }
        *(uint2*)(yb + (size_t)n * 256 + d0) = ov;
        asm volatile("" ::: "memory");
    }
}

// ---------------------------------------------------------------------------
// K4 final MFMA GEMM.
// ---------------------------------------------------------------------------
__global__ __launch_bounds__(256) void final_kernel(
    const u16* __restrict__ xb, const u16* __restrict__ yb,
    const u16* __restrict__ wpb, const float* __restrict__ bp,
    float* __restrict__ out, int reps)
{
    int t = threadIdx.x;
    int wv = t >> 6, l = t & 63, lr = l & 15, lk = l >> 4;
    int m0 = blockIdx.x * 64 + wv * 16;
    int n0 = blockIdx.y * 64;

    const short8* axp = (const short8*)(xb + (size_t)(m0 + lr) * 256 + lk * 8);
    const short8* ayp = (const short8*)(yb + (size_t)(m0 + lr) * 256 + lk * 8);
    const short8* wp_ = (const short8*)(wpb + (size_t)(n0 + lr) * 512 + lk * 8);

    for (int rep = 0; rep < reps; rep++) {
        f32x4 acc[4] = {};
        #pragma unroll
        for (int kk = 0; kk < 16; kk++) {
            short8 a = (kk < 8) ? axp[kk * 4] : ayp[(kk - 8) * 4];
            #pragma unroll
            for (int j = 0; j < 4; j++) {
                short8 b = wp_[(size_t)j * 16 * 64 + kk * 4];
                acc[j] = __builtin_amdgcn_mfma_f32_16x16x32_bf16(a, b, acc[j], 0, 0, 0);
            }
        }
        #pragma unroll
        for (int j = 0; j < 4; j++)
            #pragma unroll
            for (int r = 0; r < 4; r++) {
                int grow = m0 + lk * 4 + r;
                int gc   = n0 + j * 16 + lr;
                out[(size_t)grow * 256 + gc] = acc[j][r] + bp[gc];
            }
        asm volatile("" ::: "memory");
    }
}

// ---------------------------------------------------------------------------
extern "C" void kernel_launch(void* const* d_in, const int* in_sizes, int n_in,
                              void* d_out, int out_size, void* d_ws, size_t ws_size,
                              hipStream_t stream) {
    const float* x  = (const float*)d_in[0];
    const int*   ei = (const int*)d_in[1];
    const float* Wq = (const float*)d_in[2];
    const float* bq = (const float*)d_in[3];
    const float* Wk = (const float*)d_in[4];
    const float* bk = (const float*)d_in[5];
    const float* Wv = (const float*)d_in[6];
    const float* bv = (const float*)d_in[7];
    const float* Wp = (const float*)d_in[8];
    const float* bp = (const float*)d_in[9];
    float* out = (float*)d_out;

    const int D = 256;
    int N = in_sizes[0] / D;       // 4096
    int E = in_sizes[1] / 2;       // 135168

    size_t maskB = (size_t)N * (N >> 5) * sizeof(unsigned);   // 2 MB
    char* ws = (char*)d_ws;
    unsigned* mask  = (unsigned*)ws;
    unsigned* orbuf = (unsigned*)(ws + maskB);                // 64 words
    u16* qbb   = (u16*)(ws + maskB + 1024);
    u16* kbb   = qbb + (size_t)N * D;
    u16* vbb   = kbb + (size_t)N * D;
    u16* ybb   = vbb + (size_t)N * D;
    u16* xbb   = ybb + (size_t)N * D;
    u16* wpb   = xbb + (size_t)N * D;                         // 131072 bf16
    u16* wqkvb = wpb + 131072;                                // 196608 bf16

    prep_kernel<<<688, 256, 0, stream>>>(
        ei, E, (uint4*)ws, (int)(maskB / 16), orbuf,
        Wp, wpb, x, xbb, Wq, Wk, Wv, wqkvb, REPS);

    scatter_qkv_kernel<<<512, 256, 0, stream>>>(
        ei, E, N, mask, orbuf, xbb, wqkvb, bq, bk, bv, qbb, kbb, vbb, REPS);

    attn_kernel<<<N / 4, 256, 0, stream>>>(mask, qbb, kbb, vbb, ybb, N, REPS);

    dim3 gf(N / 64, 4);
    final_kernel<<<gf, 256, 0, stream>>>(xbb, ybb, wpb, bp, out, REPS);
}

// Round 15
// 65.494 us; speedup vs baseline: 6.4979x; 6.4979x over previous
//
#include <hip/hip_runtime.h>
#include <hip/hip_bf16.h>

typedef unsigned short u16;
typedef __attribute__((ext_vector_type(8))) short short8;   // 8 bf16 = 4 VGPR
typedef __attribute__((ext_vector_type(4))) float f32x4;

#define MAXC 256

__device__ __forceinline__ float b2f(u16 b) {
    return __uint_as_float(((unsigned)b) << 16);
}
// fp32 -> bf16 RNE
__device__ __forceinline__ u16 f2b(float f) {
    unsigned u = __float_as_uint(f);
    return (u16)((u + 0x7FFFu + ((u >> 16) & 1u)) >> 16);
}
__device__ __forceinline__ uint2 cvt4(float4 f) {
    uint2 r;
    r.x = (unsigned)f2b(f.x) | ((unsigned)f2b(f.y) << 16);
    r.y = (unsigned)f2b(f.z) | ((unsigned)f2b(f.w) << 16);
    return r;
}

// ---------------------------------------------------------------------------
// K1 prep, 5 parallel roles (R11-proven, single-shot).
// ---------------------------------------------------------------------------
__global__ __launch_bounds__(256) void prep_kernel(
    const int* __restrict__ e, int E,
    uint4* __restrict__ maskv, int mask16, unsigned* __restrict__ orbuf,
    const float* __restrict__ Wp, u16* __restrict__ wpb,
    const float* __restrict__ x,  u16* __restrict__ xb,
    const float* __restrict__ Wq, const float* __restrict__ Wk,
    const float* __restrict__ Wv, u16* __restrict__ wqkvb)
{
    int b = blockIdx.x, t = threadIdx.x;
    if (b < 192) {
        uint4 z = {0u, 0u, 0u, 0u};
        for (int i = b * 256 + t; i < mask16; i += 192 * 256) maskv[i] = z;
    } else if (b < 256) {
        int bb = b - 192;
        unsigned acc = 0;
        for (int i = bb * 256 + t; i < E; i += 64 * 256)
            acc |= (unsigned)e[2 * i + 1];
        __shared__ unsigned red[4];
        #pragma unroll
        for (int o = 32; o > 0; o >>= 1) acc |= __shfl_xor(acc, o, 64);
        if ((t & 63) == 0) red[t >> 6] = acc;
        __syncthreads();
        if (t == 0) orbuf[bb] = red[0] | red[1] | red[2] | red[3];
    } else if (b < 384) {
        int i = (b - 256) * 256 + t;                  // 32768 slots
        *(uint2*)(wpb + 4 * (size_t)i) = cvt4(((const float4*)Wp)[i]);
    } else if (b < 640) {
        int base = (b - 384) * 1024;                  // 262144 slots
        #pragma unroll
        for (int r = 0; r < 4; r++) {
            int i = base + r * 256 + t;
            *(uint2*)(xb + 4 * (size_t)i) = cvt4(((const float4*)x)[i]);
        }
    } else {
        int base = (b - 640) * 1024;                  // 49152 slots
        #pragma unroll
        for (int r = 0; r < 4; r++) {
            int i = base + r * 256 + t;
            float4 f;
            if (i < 16384)      f = ((const float4*)Wq)[i];
            else if (i < 32768) f = ((const float4*)Wk)[i - 16384];
            else                f = ((const float4*)Wv)[i - 32768];
            *(uint2*)(wqkvb + 4 * (size_t)i) = cvt4(f);
        }
    }
}

// ---------------------------------------------------------------------------
// K2 fused scatter + QKV MFMA GEMM (R11-proven, single-shot).
// ---------------------------------------------------------------------------
__global__ __launch_bounds__(256) void scatter_qkv_kernel(
    const int* __restrict__ e, int E, int N,
    unsigned* __restrict__ mask, const unsigned* __restrict__ orbuf,
    const u16* __restrict__ xb, const u16* __restrict__ wqkvb,
    const float* __restrict__ bq, const float* __restrict__ bk,
    const float* __restrict__ bv,
    u16* __restrict__ q, u16* __restrict__ k, u16* __restrict__ v)
{
    int t = threadIdx.x;

    if (blockIdx.x < 128) {
        unsigned oo = orbuf[t & 63];
        #pragma unroll
        for (int o = 32; o > 0; o >>= 1) oo |= __shfl_xor(oo, o, 64);
        bool i32mode = (oo != 0);
        int nw = N >> 5;
        for (int i = blockIdx.x * 256 + t; i < E; i += 128 * 256) {
            int row, col;
            if (i32mode) { row = e[i];     col = e[E + i]; }
            else         { row = e[2 * i]; col = e[2 * E + 2 * i]; }
            if ((unsigned)row < (unsigned)N && (unsigned)col < (unsigned)N)
                atomicOr(&mask[(size_t)row * nw + (col >> 5)], 1u << (col & 31));
        }
        return;
    }

    int bid = blockIdx.x - 128;                // 0..383
    int bx = bid & 31, by = bid >> 5;          // 32 row tiles x 12 col groups
    int which = by >> 2;                       // 0=q 1=k 2=v
    int ncl = (by & 3) * 64;                   // col base within 256
    int n0f = which * 256 + ncl;               // row base in fused Wqkv
    const float* bias = (which == 0) ? bq : (which == 1) ? bk : bv;
    u16*         T    = (which == 0) ? q  : (which == 1) ? k  : v;

    int wv = t >> 6, l = t & 63, lr = l & 15, lk = l >> 4;
    int m0 = bx * 128 + wv * 32;
    f32x4 acc[2][4] = {};
    const short8* a0p = (const short8*)(xb + (size_t)(m0 + lr) * 256 + lk * 8);
    const short8* a1p = (const short8*)(xb + (size_t)(m0 + 16 + lr) * 256 + lk * 8);
    const short8* wp_ = (const short8*)(wqkvb + (size_t)(n0f + lr) * 256 + lk * 8);

    #pragma unroll
    for (int kk = 0; kk < 8; kk++) {
        short8 a0 = a0p[kk * 4];               // +32 bf16 per k-step
        short8 a1 = a1p[kk * 4];
        #pragma unroll
        for (int j = 0; j < 4; j++) {
            short8 b = wp_[(size_t)j * 16 * 32 + kk * 4];   // +16 rows = 16*256 bf16
            acc[0][j] = __builtin_amdgcn_mfma_f32_16x16x32_bf16(a0, b, acc[0][j], 0, 0, 0);
            acc[1][j] = __builtin_amdgcn_mfma_f32_16x16x32_bf16(a1, b, acc[1][j], 0, 0, 0);
        }
    }
    #pragma unroll
    for (int i2 = 0; i2 < 2; i2++)
        #pragma unroll
        for (int j = 0; j < 4; j++)
            #pragma unroll
            for (int r = 0; r < 4; r++) {
                int grow = m0 + i2 * 16 + lk * 4 + r;
                int gc   = ncl + j * 16 + lr;
                T[(size_t)grow * 256 + gc] = f2b(acc[i2][j][r] + bias[gc]);
            }
}

// ---------------------------------------------------------------------------
// K3 attn v3: TWO WAVES PER ROW (wave = 4 heads / 128 dims), two-pass softmax.
// R14 attribution: attn = 18.6us warm, VALUBusy 33%, VGPR 68 (-> only 16
// waves/CU: 68 > 64 boundary), 3 serialized shuffle-merge cascades per row.
// Fixes: (1) __launch_bounds__(256,8) caps VGPR at 64 -> 32 waves/CU, and
// 2 waves/row doubles wave count to 8192 to fill them; per-wave chain
// halves. (2) two-pass softmax per 64-macro-chunk: 4 INDEPENDENT score
// sub-chunks (loads/dots overlap), then ONE max-merge + ONE sum-merge
// (3x fewer serialized ds-cascades; exp chain 6 -> 2). Scores staged in
// LDS, weights computed in-place. cols padded to x64 -> all loop bounds
// compile-time. Macro-chunks >1 (cnt>64, ~never) merge online.
// ---------------------------------------------------------------------------
__global__ __launch_bounds__(256, 8) void attn_kernel(
    const unsigned* __restrict__ mask,
    const u16* __restrict__ qb, const u16* __restrict__ kb,
    const u16* __restrict__ vb, u16* __restrict__ yb, int N)
{
    __shared__ int   cols[4][MAXC];     // per wave
    __shared__ float ss[4][4][68];      // per wave x head: scores -> weights (in place)
    __shared__ float fs[4][4];
    __shared__ float lsums[4][4];

    int t = threadIdx.x;
    int wv = t >> 6, lane = t & 63;
    int n  = blockIdx.x * 2 + (wv >> 1);   // 2 rows per block
    int hb = (wv & 1) * 4;                 // this wave's head base (4 heads)
    int nw = N >> 5;                       // 128

    // ---- per-wave compaction (duplicated across the row's 2 waves) ----
    unsigned wa = mask[(size_t)n * nw + lane];
    unsigned wb = mask[(size_t)n * nw + 64 + lane];
    int pc = __popc(wa) + __popc(wb);
    int scan = pc;
    #pragma unroll
    for (int o = 1; o < 64; o <<= 1) {
        int pv = __shfl_up(scan, o, 64);
        if (lane >= o) scan += pv;
    }
    int cnt = __shfl(scan, 63, 64);
    if (cnt > MAXC) cnt = MAXC;
    int off = scan - pc;
    while (wa && off < MAXC) {
        int b = __ffs(wa) - 1; wa &= wa - 1;
        cols[wv][off++] = (lane << 5) + b;
    }
    while (wb && off < MAXC) {
        int b = __ffs(wb) - 1; wb &= wb - 1;
        cols[wv][off++] = ((64 + lane) << 5) + b;
    }
    int cntp = (cnt + 63) & ~63;           // pad to x64 with self-index
    if (cntp > MAXC) cntp = MAXC;
    for (int i = cnt + lane; i < cntp; i += 64) cols[wv][i] = n;
    asm volatile("s_waitcnt lgkmcnt(0)" ::: "memory");

    int h  = lane >> 4;                    // score head (hb+h); also V dim-head
    int jl = lane & 15;                    // neighbor slot within sub-chunk
    int d0 = hb * 32 + lane * 2;           // V dims d0, d0+1 (contiguous 256B/wave)

    const short8* qp = (const short8*)(qb + (size_t)n * 256 + (hb + h) * 32);
    short8 q0 = qp[0], q1 = qp[1];

    const float scale = 0.17677669529663687f;   // 1/sqrt(32)
    float mx = -1e30f, lsum = 0.f, acc0 = 0.f, acc1 = 0.f;

    for (int m0 = 0; m0 < cntp; m0 += 64) {
        // --- pass 1: scores (4 independent sub-chunks, 1 dot/lane each) ---
        float lmax = -1e30f;
        #pragma unroll
        for (int sci = 0; sci < 4; sci++) {
            int j = m0 + sci * 16 + jl;
            const u16* kr = kb + (size_t)cols[wv][j] * 256 + (hb + h) * 32;
            short8 a0 = ((const short8*)kr)[0];
            short8 a1 = ((const short8*)kr)[1];
            float sa = 0.f;
            #pragma unroll
            for (int e2 = 0; e2 < 8; e2++) {
                sa = fmaf(b2f((u16)a0[e2]), b2f((u16)q0[e2]), sa);
                sa = fmaf(b2f((u16)a1[e2]), b2f((u16)q1[e2]), sa);
            }
            float s = (j < cnt) ? sa * scale : -1e30f;
            ss[wv][h][sci * 16 + jl] = s;
            lmax = fmaxf(lmax, s);
        }
        // --- single merge: max, then weights + sum ---
        #pragma unroll
        for (int o = 8; o > 0; o >>= 1) lmax = fmaxf(lmax, __shfl_xor(lmax, o, 16));
        float mnew = fmaxf(mx, lmax);
        float f = __expf(mx - mnew);       // first macro: exp(-inf)=0, harmless
        asm volatile("s_waitcnt lgkmcnt(0)" ::: "memory");
        float psum = 0.f;
        #pragma unroll
        for (int sci = 0; sci < 4; sci++) {
            float s = ss[wv][h][sci * 16 + jl];
            float w = __expf(s - mnew);    // padded slots: exp(-huge)=0
            ss[wv][h][sci * 16 + jl] = w;
            psum += w;
        }
        #pragma unroll
        for (int o = 8; o > 0; o >>= 1) psum += __shfl_xor(psum, o, 16);
        lsum = lsum * f + psum;
        mx = mnew;
        if (jl == 0) fs[wv][h] = f;
        asm volatile("s_waitcnt lgkmcnt(0)" ::: "memory");

        // --- V accumulation: 64 neighbors, 2 dims/lane, w broadcast from LDS ---
        float fv = fs[wv][h];
        acc0 *= fv; acc1 *= fv;
        #pragma unroll 1
        for (int sc = 0; sc < 64; sc += 16) {
            #pragma unroll
            for (int jj = 0; jj < 16; jj++) {
                int j = m0 + sc + jj;
                float wj = ss[wv][h][sc + jj];
                unsigned raw = *(const unsigned*)(vb + (size_t)cols[wv][j] * 256 + d0);
                acc0 = fmaf(wj, b2f((u16)(raw & 0xffff)), acc0);
                acc1 = fmaf(wj, b2f((u16)(raw >> 16)),    acc1);
            }
        }
    }

    if (jl == 0) lsums[wv][h] = lsum;
    asm volatile("s_waitcnt lgkmcnt(0)" ::: "memory");
    float ls = lsums[wv][h];
    unsigned ov = 0u;
    if (cnt > 0)
        ov = (unsigned)f2b(acc0 / ls) | ((unsigned)f2b(acc1 / ls) << 16);
    *(unsigned*)(yb + (size_t)n * 256 + d0) = ov;
}

// ---------------------------------------------------------------------------
// K4 final MFMA GEMM: out = [xb | y] @ Wp^T + bp, K=512, fp32 out
// (R11-proven, single-shot).
// ---------------------------------------------------------------------------
__global__ __launch_bounds__(256) void final_kernel(
    const u16* __restrict__ xb, const u16* __restrict__ yb,
    const u16* __restrict__ wpb, const float* __restrict__ bp,
    float* __restrict__ out)
{
    int t = threadIdx.x;
    int wv = t >> 6, l = t & 63, lr = l & 15, lk = l >> 4;
    int m0 = blockIdx.x * 64 + wv * 16;
    int n0 = blockIdx.y * 64;

    f32x4 acc[4] = {};
    const short8* axp = (const short8*)(xb + (size_t)(m0 + lr) * 256 + lk * 8);
    const short8* ayp = (const short8*)(yb + (size_t)(m0 + lr) * 256 + lk * 8);
    const short8* wp_ = (const short8*)(wpb + (size_t)(n0 + lr) * 512 + lk * 8);

    #pragma unroll
    for (int kk = 0; kk < 16; kk++) {
        short8 a = (kk < 8) ? axp[kk * 4] : ayp[(kk - 8) * 4];
        #pragma unroll
        for (int j = 0; j < 4; j++) {
            short8 b = wp_[(size_t)j * 16 * 64 + kk * 4];   // +16 rows = 16*512 bf16
            acc[j] = __builtin_amdgcn_mfma_f32_16x16x32_bf16(a, b, acc[j], 0, 0, 0);
        }
    }
    #pragma unroll
    for (int j = 0; j < 4; j++)
        #pragma unroll
        for (int r = 0; r < 4; r++) {
            int grow = m0 + lk * 4 + r;
            int gc   = n0 + j * 16 + lr;
            out[(size_t)grow * 256 + gc] = acc[j][r] + bp[gc];
        }
}

// ---------------------------------------------------------------------------
extern "C" void kernel_launch(void* const* d_in, const int* in_sizes, int n_in,
                              void* d_out, int out_size, void* d_ws, size_t ws_size,
                              hipStream_t stream) {
    const float* x  = (const float*)d_in[0];
    const int*   ei = (const int*)d_in[1];
    const float* Wq = (const float*)d_in[2];
    const float* bq = (const float*)d_in[3];
    const float* Wk = (const float*)d_in[4];
    const float* bk = (const float*)d_in[5];
    const float* Wv = (const float*)d_in[6];
    const float* bv = (const float*)d_in[7];
    const float* Wp = (const float*)d_in[8];
    const float* bp = (const float*)d_in[9];
    float* out = (float*)d_out;

    const int D = 256;
    int N = in_sizes[0] / D;       // 4096
    int E = in_sizes[1] / 2;       // 135168

    size_t maskB = (size_t)N * (N >> 5) * sizeof(unsigned);   // 2 MB
    char* ws = (char*)d_ws;
    unsigned* mask  = (unsigned*)ws;
    unsigned* orbuf = (unsigned*)(ws + maskB);                // 64 words
    u16* qbb   = (u16*)(ws + maskB + 1024);
    u16* kbb   = qbb + (size_t)N * D;
    u16* vbb   = kbb + (size_t)N * D;
    u16* ybb   = vbb + (size_t)N * D;
    u16* xbb   = ybb + (size_t)N * D;
    u16* wpb   = xbb + (size_t)N * D;                         // 131072 bf16
    u16* wqkvb = wpb + 131072;                                // 196608 bf16

    prep_kernel<<<688, 256, 0, stream>>>(
        ei, E, (uint4*)ws, (int)(maskB / 16), orbuf,
        Wp, wpb, x, xbb, Wq, Wk, Wv, wqkvb);

    scatter_qkv_kernel<<<512, 256, 0, stream>>>(
        ei, E, N, mask, orbuf, xbb, wqkvb, bq, bk, bv, qbb, kbb, vbb);

    attn_kernel<<<N / 2, 256, 0, stream>>>(mask, qbb, kbb, vbb, ybb, N);

    dim3 gf(N / 64, 4);
    final_kernel<<<gf, 256, 0, stream>>>(xbb, ybb, wpb, bp, out);
}

// Round 16
// 57.297 us; speedup vs baseline: 7.4275x; 1.1431x over previous
//
#include <hip/hip_runtime.h>
#include <hip/hip_bf16.h>

typedef unsigned short u16;
typedef __attribute__((ext_vector_type(8))) short short8;   // 8 bf16 = 4 VGPR
typedef __attribute__((ext_vector_type(4))) float f32x4;

#define MAXC 256

__device__ __forceinline__ float b2f(u16 b) {
    return __uint_as_float(((unsigned)b) << 16);
}
// fp32 -> bf16 RNE
__device__ __forceinline__ u16 f2b(float f) {
    unsigned u = __float_as_uint(f);
    return (u16)((u + 0x7FFFu + ((u >> 16) & 1u)) >> 16);
}
__device__ __forceinline__ uint2 cvt4(float4 f) {
    uint2 r;
    r.x = (unsigned)f2b(f.x) | ((unsigned)f2b(f.y) << 16);
    r.y = (unsigned)f2b(f.z) | ((unsigned)f2b(f.w) << 16);
    return r;
}

// ---------------------------------------------------------------------------
// K1 prep, 5 parallel roles (R11-proven, single-shot).
// ---------------------------------------------------------------------------
__global__ __launch_bounds__(256) void prep_kernel(
    const int* __restrict__ e, int E,
    uint4* __restrict__ maskv, int mask16, unsigned* __restrict__ orbuf,
    const float* __restrict__ Wp, u16* __restrict__ wpb,
    const float* __restrict__ x,  u16* __restrict__ xb,
    const float* __restrict__ Wq, const float* __restrict__ Wk,
    const float* __restrict__ Wv, u16* __restrict__ wqkvb)
{
    int b = blockIdx.x, t = threadIdx.x;
    if (b < 192) {
        uint4 z = {0u, 0u, 0u, 0u};
        for (int i = b * 256 + t; i < mask16; i += 192 * 256) maskv[i] = z;
    } else if (b < 256) {
        int bb = b - 192;
        unsigned acc = 0;
        for (int i = bb * 256 + t; i < E; i += 64 * 256)
            acc |= (unsigned)e[2 * i + 1];
        __shared__ unsigned red[4];
        #pragma unroll
        for (int o = 32; o > 0; o >>= 1) acc |= __shfl_xor(acc, o, 64);
        if ((t & 63) == 0) red[t >> 6] = acc;
        __syncthreads();
        if (t == 0) orbuf[bb] = red[0] | red[1] | red[2] | red[3];
    } else if (b < 384) {
        int i = (b - 256) * 256 + t;                  // 32768 slots
        *(uint2*)(wpb + 4 * (size_t)i) = cvt4(((const float4*)Wp)[i]);
    } else if (b < 640) {
        int base = (b - 384) * 1024;                  // 262144 slots
        #pragma unroll
        for (int r = 0; r < 4; r++) {
            int i = base + r * 256 + t;
            *(uint2*)(xb + 4 * (size_t)i) = cvt4(((const float4*)x)[i]);
        }
    } else {
        int base = (b - 640) * 1024;                  // 49152 slots
        #pragma unroll
        for (int r = 0; r < 4; r++) {
            int i = base + r * 256 + t;
            float4 f;
            if (i < 16384)      f = ((const float4*)Wq)[i];
            else if (i < 32768) f = ((const float4*)Wk)[i - 16384];
            else                f = ((const float4*)Wv)[i - 32768];
            *(uint2*)(wqkvb + 4 * (size_t)i) = cvt4(f);
        }
    }
}

// ---------------------------------------------------------------------------
// K2 fused scatter + QKV MFMA GEMM (R11-proven, single-shot).
// ---------------------------------------------------------------------------
__global__ __launch_bounds__(256) void scatter_qkv_kernel(
    const int* __restrict__ e, int E, int N,
    unsigned* __restrict__ mask, const unsigned* __restrict__ orbuf,
    const u16* __restrict__ xb, const u16* __restrict__ wqkvb,
    const float* __restrict__ bq, const float* __restrict__ bk,
    const float* __restrict__ bv,
    u16* __restrict__ q, u16* __restrict__ k, u16* __restrict__ v)
{
    int t = threadIdx.x;

    if (blockIdx.x < 128) {
        unsigned oo = orbuf[t & 63];
        #pragma unroll
        for (int o = 32; o > 0; o >>= 1) oo |= __shfl_xor(oo, o, 64);
        bool i32mode = (oo != 0);
        int nw = N >> 5;
        for (int i = blockIdx.x * 256 + t; i < E; i += 128 * 256) {
            int row, col;
            if (i32mode) { row = e[i];     col = e[E + i]; }
            else         { row = e[2 * i]; col = e[2 * E + 2 * i]; }
            if ((unsigned)row < (unsigned)N && (unsigned)col < (unsigned)N)
                atomicOr(&mask[(size_t)row * nw + (col >> 5)], 1u << (col & 31));
        }
        return;
    }

    int bid = blockIdx.x - 128;                // 0..383
    int bx = bid & 31, by = bid >> 5;          // 32 row tiles x 12 col groups
    int which = by >> 2;                       // 0=q 1=k 2=v
    int ncl = (by & 3) * 64;                   // col base within 256
    int n0f = which * 256 + ncl;               // row base in fused Wqkv
    const float* bias = (which == 0) ? bq : (which == 1) ? bk : bv;
    u16*         T    = (which == 0) ? q  : (which == 1) ? k  : v;

    int wv = t >> 6, l = t & 63, lr = l & 15, lk = l >> 4;
    int m0 = bx * 128 + wv * 32;
    f32x4 acc[2][4] = {};
    const short8* a0p = (const short8*)(xb + (size_t)(m0 + lr) * 256 + lk * 8);
    const short8* a1p = (const short8*)(xb + (size_t)(m0 + 16 + lr) * 256 + lk * 8);
    const short8* wp_ = (const short8*)(wqkvb + (size_t)(n0f + lr) * 256 + lk * 8);

    #pragma unroll
    for (int kk = 0; kk < 8; kk++) {
        short8 a0 = a0p[kk * 4];               // +32 bf16 per k-step
        short8 a1 = a1p[kk * 4];
        #pragma unroll
        for (int j = 0; j < 4; j++) {
            short8 b = wp_[(size_t)j * 16 * 32 + kk * 4];   // +16 rows = 16*256 bf16
            acc[0][j] = __builtin_amdgcn_mfma_f32_16x16x32_bf16(a0, b, acc[0][j], 0, 0, 0);
            acc[1][j] = __builtin_amdgcn_mfma_f32_16x16x32_bf16(a1, b, acc[1][j], 0, 0, 0);
        }
    }
    #pragma unroll
    for (int i2 = 0; i2 < 2; i2++)
        #pragma unroll
        for (int j = 0; j < 4; j++)
            #pragma unroll
            for (int r = 0; r < 4; r++) {
                int grow = m0 + i2 * 16 + lk * 4 + r;
                int gc   = ncl + j * 16 + lr;
                T[(size_t)grow * 256 + gc] = f2b(acc[i2][j][r] + bias[gc]);
            }
}

// ---------------------------------------------------------------------------
// K3 attn v4: R10's proven skeleton (1 wave/row, 4 waves/block, 8B V loads,
// no forced launch bounds) with ONE change: macro-chunk=64, SINGLE softmax
// merge. 4x16 score sub-chunks are mutually independent (loads/dots overlap,
// compiler-scheduled); ONE max cascade + ONE sum cascade + one fs round-trip
// per 64 neighbors (vs 3 full merge rounds in R10 at cnt~33). V phase: 64
// neighbors, sub-groups independent -> latencies overlap. ws padded [8][66]
// to avoid 8-way LDS bank aliasing (64 = 0 mod 32 banks). cnt>64 (~never,
// Poisson(32)) -> online merge across macro-chunks (R15-proven math).
// R15's regressions avoided: no dup compaction, no VGPR cap, no 4B loads,
// no forced serial unroll.
// ---------------------------------------------------------------------------
__global__ __launch_bounds__(256) void attn_kernel(
    const unsigned* __restrict__ mask,
    const u16* __restrict__ qb, const u16* __restrict__ kb,
    const u16* __restrict__ vb, u16* __restrict__ yb, int N)
{
    __shared__ int   cols[4][MAXC];
    __shared__ float ws[4][8][66];      // pad 66: head stride 66 % 32 = 2 banks
    __shared__ float fs[4][8];
    __shared__ float lsums[4][8];

    int t = threadIdx.x;
    int wv = t >> 6, lane = t & 63;
    int n = blockIdx.x * 4 + wv;
    int nw = N >> 5;                        // 128

    // ---- per-wave compaction (R10-proven; pad to x64 with self-index) ----
    unsigned wa = mask[(size_t)n * nw + lane];
    unsigned wb = mask[(size_t)n * nw + 64 + lane];
    int pc = __popc(wa) + __popc(wb);
    int scan = pc;
    #pragma unroll
    for (int o = 1; o < 64; o <<= 1) {
        int pv = __shfl_up(scan, o, 64);
        if (lane >= o) scan += pv;
    }
    int cnt = __shfl(scan, 63, 64);
    if (cnt > MAXC) cnt = MAXC;
    int off = scan - pc;
    while (wa && off < MAXC) {
        int b = __ffs(wa) - 1; wa &= wa - 1;
        cols[wv][off++] = (lane << 5) + b;
    }
    while (wb && off < MAXC) {
        int b = __ffs(wb) - 1; wb &= wb - 1;
        cols[wv][off++] = ((64 + lane) << 5) + b;
    }
    int cntp = (cnt + 63) & ~63;
    if (cntp > MAXC) cntp = MAXC;
    for (int i = cnt + lane; i < cntp; i += 64) cols[wv][i] = n;
    asm volatile("s_waitcnt lgkmcnt(0)" ::: "memory");

    int h8 = lane >> 4;                 // head pair (h8, h8+4)
    int jl = lane & 15;                 // neighbor slot within sub-chunk
    int hv = lane >> 3;                 // V-phase head
    int d0 = lane * 4;                  // V-phase dims d0..d0+3

    const short8* qpA = (const short8*)(qb + (size_t)n * 256 + h8 * 32);
    const short8* qpB = (const short8*)(qb + (size_t)n * 256 + (h8 + 4) * 32);
    short8 qA0 = qpA[0], qA1 = qpA[1];
    short8 qB0 = qpB[0], qB1 = qpB[1];

    const float scale = 0.17677669529663687f;   // 1/sqrt(32)
    float mxA = -1e30f, mxB = -1e30f, lsA = 0.f, lsB = 0.f;
    float acc0 = 0.f, acc1 = 0.f, acc2 = 0.f, acc3 = 0.f;

    for (int m0 = 0; m0 < cntp; m0 += 64) {
        // --- scores: 4 independent 16-neighbor sub-chunks, 2 heads/lane ---
        float sA[4], sB[4];
        #pragma unroll
        for (int sci = 0; sci < 4; sci++) {
            int j = m0 + sci * 16 + jl;
            const u16* kr = kb + (size_t)cols[wv][j] * 256;
            short8 a0 = ((const short8*)(kr + h8 * 32))[0];
            short8 a1 = ((const short8*)(kr + h8 * 32))[1];
            short8 b0 = ((const short8*)(kr + (h8 + 4) * 32))[0];
            short8 b1 = ((const short8*)(kr + (h8 + 4) * 32))[1];
            float sa = 0.f, sb = 0.f;
            #pragma unroll
            for (int e2 = 0; e2 < 8; e2++) {
                sa = fmaf(b2f((u16)a0[e2]), b2f((u16)qA0[e2]), sa);
                sa = fmaf(b2f((u16)a1[e2]), b2f((u16)qA1[e2]), sa);
                sb = fmaf(b2f((u16)b0[e2]), b2f((u16)qB0[e2]), sb);
                sb = fmaf(b2f((u16)b1[e2]), b2f((u16)qB1[e2]), sb);
            }
            bool valid = j < cnt;
            sA[sci] = valid ? sa * scale : -1e30f;
            sB[sci] = valid ? sb * scale : -1e30f;
        }

        // --- SINGLE merge for 64 neighbors ---
        float cmA = fmaxf(fmaxf(sA[0], sA[1]), fmaxf(sA[2], sA[3]));
        float cmB = fmaxf(fmaxf(sB[0], sB[1]), fmaxf(sB[2], sB[3]));
        #pragma unroll
        for (int o = 8; o > 0; o >>= 1) {
            cmA = fmaxf(cmA, __shfl_xor(cmA, o, 16));
            cmB = fmaxf(cmB, __shfl_xor(cmB, o, 16));
        }
        float mnA = fmaxf(mxA, cmA), mnB = fmaxf(mxB, cmB);
        float fA = __expf(mxA - mnA), fB = __expf(mxB - mnB);
        float psA = 0.f, psB = 0.f;
        float wAv[4], wBv[4];
        #pragma unroll
        for (int sci = 0; sci < 4; sci++) {
            wAv[sci] = __expf(sA[sci] - mnA);    // padded: exp(-huge)=0
            wBv[sci] = __expf(sB[sci] - mnB);
            psA += wAv[sci];
            psB += wBv[sci];
        }
        #pragma unroll
        for (int o = 8; o > 0; o >>= 1) {
            psA += __shfl_xor(psA, o, 16);
            psB += __shfl_xor(psB, o, 16);
        }
        lsA = lsA * fA + psA;  lsB = lsB * fB + psB;
        mxA = mnA;             mxB = mnB;

        #pragma unroll
        for (int sci = 0; sci < 4; sci++) {
            ws[wv][h8][sci * 16 + jl]     = wAv[sci];
            ws[wv][h8 + 4][sci * 16 + jl] = wBv[sci];
        }
        if (jl == 0) { fs[wv][h8] = fA; fs[wv][h8 + 4] = fB; }
        asm volatile("s_waitcnt lgkmcnt(0)" ::: "memory");

        // --- V: 64 neighbors, 4 dims/lane, 8B loads; sub-groups independent ---
        float fv = fs[wv][hv];
        acc0 *= fv; acc1 *= fv; acc2 *= fv; acc3 *= fv;
        for (int sc = 0; sc < 64; sc += 16) {
            #pragma unroll
            for (int jj = 0; jj < 16; jj++) {
                int j = m0 + sc + jj;
                float wj = ws[wv][hv][sc + jj];
                uint2 raw = *(const uint2*)(vb + (size_t)cols[wv][j] * 256 + d0);
                acc0 = fmaf(wj, b2f((u16)(raw.x & 0xffff)), acc0);
                acc1 = fmaf(wj, b2f((u16)(raw.x >> 16)),    acc1);
                acc2 = fmaf(wj, b2f((u16)(raw.y & 0xffff)), acc2);
                acc3 = fmaf(wj, b2f((u16)(raw.y >> 16)),    acc3);
            }
        }
    }

    if (jl == 0) { lsums[wv][h8] = lsA; lsums[wv][h8 + 4] = lsB; }
    asm volatile("s_waitcnt lgkmcnt(0)" ::: "memory");
    float ls = lsums[wv][hv];
    uint2 ov;
    if (cnt > 0) {
        ov.x = (unsigned)f2b(acc0 / ls) | ((unsigned)f2b(acc1 / ls) << 16);
        ov.y = (unsigned)f2b(acc2 / ls) | ((unsigned)f2b(acc3 / ls) << 16);
    } else {
        ov.x = 0u; ov.y = 0u;
    }
    *(uint2*)(yb + (size_t)n * 256 + d0) = ov;
}

// ---------------------------------------------------------------------------
// K4 final MFMA GEMM: out = [xb | y] @ Wp^T + bp, K=512, fp32 out
// (R11-proven, single-shot).
// ---------------------------------------------------------------------------
__global__ __launch_bounds__(256) void final_kernel(
    const u16* __restrict__ xb, const u16* __restrict__ yb,
    const u16* __restrict__ wpb, const float* __restrict__ bp,
    float* __restrict__ out)
{
    int t = threadIdx.x;
    int wv = t >> 6, l = t & 63, lr = l & 15, lk = l >> 4;
    int m0 = blockIdx.x * 64 + wv * 16;
    int n0 = blockIdx.y * 64;

    f32x4 acc[4] = {};
    const short8* axp = (const short8*)(xb + (size_t)(m0 + lr) * 256 + lk * 8);
    const short8* ayp = (const short8*)(yb + (size_t)(m0 + lr) * 256 + lk * 8);
    const short8* wp_ = (const short8*)(wpb + (size_t)(n0 + lr) * 512 + lk * 8);

    #pragma unroll
    for (int kk = 0; kk < 16; kk++) {
        short8 a = (kk < 8) ? axp[kk * 4] : ayp[(kk - 8) * 4];
        #pragma unroll
        for (int j = 0; j < 4; j++) {
            short8 b = wp_[(size_t)j * 16 * 64 + kk * 4];   // +16 rows = 16*512 bf16
            acc[j] = __builtin_amdgcn_mfma_f32_16x16x32_bf16(a, b, acc[j], 0, 0, 0);
        }
    }
    #pragma unroll
    for (int j = 0; j < 4; j++)
        #pragma unroll
        for (int r = 0; r < 4; r++) {
            int grow = m0 + lk * 4 + r;
            int gc   = n0 + j * 16 + lr;
            out[(size_t)grow * 256 + gc] = acc[j][r] + bp[gc];
        }
}

// ---------------------------------------------------------------------------
extern "C" void kernel_launch(void* const* d_in, const int* in_sizes, int n_in,
                              void* d_out, int out_size, void* d_ws, size_t ws_size,
                              hipStream_t stream) {
    const float* x  = (const float*)d_in[0];
    const int*   ei = (const int*)d_in[1];
    const float* Wq = (const float*)d_in[2];
    const float* bq = (const float*)d_in[3];
    const float* Wk = (const float*)d_in[4];
    const float* bk = (const float*)d_in[5];
    const float* Wv = (const float*)d_in[6];
    const float* bv = (const float*)d_in[7];
    const float* Wp = (const float*)d_in[8];
    const float* bp = (const float*)d_in[9];
    float* out = (float*)d_out;

    const int D = 256;
    int N = in_sizes[0] / D;       // 4096
    int E = in_sizes[1] / 2;       // 135168

    size_t maskB = (size_t)N * (N >> 5) * sizeof(unsigned);   // 2 MB
    char* ws = (char*)d_ws;
    unsigned* mask  = (unsigned*)ws;
    unsigned* orbuf = (unsigned*)(ws + maskB);                // 64 words
    u16* qbb   = (u16*)(ws + maskB + 1024);
    u16* kbb   = qbb + (size_t)N * D;
    u16* vbb   = kbb + (size_t)N * D;
    u16* ybb   = vbb + (size_t)N * D;
    u16* xbb   = ybb + (size_t)N * D;
    u16* wpb   = xbb + (size_t)N * D;                         // 131072 bf16
    u16* wqkvb = wpb + 131072;                                // 196608 bf16

    prep_kernel<<<688, 256, 0, stream>>>(
        ei, E, (uint4*)ws, (int)(maskB / 16), orbuf,
        Wp, wpb, x, xbb, Wq, Wk, Wv, wqkvb);

    scatter_qkv_kernel<<<512, 256, 0, stream>>>(
        ei, E, N, mask, orbuf, xbb, wqkvb, bq, bk, bv, qbb, kbb, vbb);

    attn_kernel<<<N / 4, 256, 0, stream>>>(mask, qbb, kbb, vbb, ybb, N);

    dim3 gf(N / 64, 4);
    final_kernel<<<gf, 256, 0, stream>>>(xbb, ybb, wpb, bp, out);
}

// Round 17
// 53.468 us; speedup vs baseline: 7.9594x; 1.0716x over previous
//
#include <hip/hip_runtime.h>
#include <hip/hip_bf16.h>

typedef unsigned short u16;
typedef __attribute__((ext_vector_type(8))) short short8;   // 8 bf16 = 4 VGPR
typedef __attribute__((ext_vector_type(4))) float f32x4;

#define MAXC 256

__device__ __forceinline__ float b2f(u16 b) {
    return __uint_as_float(((unsigned)b) << 16);
}
// fp32 -> bf16 RNE
__device__ __forceinline__ u16 f2b(float f) {
    unsigned u = __float_as_uint(f);
    return (u16)((u + 0x7FFFu + ((u >> 16) & 1u)) >> 16);
}
__device__ __forceinline__ uint2 cvt4(float4 f) {
    uint2 r;
    r.x = (unsigned)f2b(f.x) | ((unsigned)f2b(f.y) << 16);
    r.y = (unsigned)f2b(f.z) | ((unsigned)f2b(f.w) << 16);
    return r;
}

// ---------------------------------------------------------------------------
// K1 prep, 5 parallel roles (R11-proven, single-shot).
// ---------------------------------------------------------------------------
__global__ __launch_bounds__(256) void prep_kernel(
    const int* __restrict__ e, int E,
    uint4* __restrict__ maskv, int mask16, unsigned* __restrict__ orbuf,
    const float* __restrict__ Wp, u16* __restrict__ wpb,
    const float* __restrict__ x,  u16* __restrict__ xb,
    const float* __restrict__ Wq, const float* __restrict__ Wk,
    const float* __restrict__ Wv, u16* __restrict__ wqkvb)
{
    int b = blockIdx.x, t = threadIdx.x;
    if (b < 192) {
        uint4 z = {0u, 0u, 0u, 0u};
        for (int i = b * 256 + t; i < mask16; i += 192 * 256) maskv[i] = z;
    } else if (b < 256) {
        int bb = b - 192;
        unsigned acc = 0;
        for (int i = bb * 256 + t; i < E; i += 64 * 256)
            acc |= (unsigned)e[2 * i + 1];
        __shared__ unsigned red[4];
        #pragma unroll
        for (int o = 32; o > 0; o >>= 1) acc |= __shfl_xor(acc, o, 64);
        if ((t & 63) == 0) red[t >> 6] = acc;
        __syncthreads();
        if (t == 0) orbuf[bb] = red[0] | red[1] | red[2] | red[3];
    } else if (b < 384) {
        int i = (b - 256) * 256 + t;                  // 32768 slots
        *(uint2*)(wpb + 4 * (size_t)i) = cvt4(((const float4*)Wp)[i]);
    } else if (b < 640) {
        int base = (b - 384) * 1024;                  // 262144 slots
        #pragma unroll
        for (int r = 0; r < 4; r++) {
            int i = base + r * 256 + t;
            *(uint2*)(xb + 4 * (size_t)i) = cvt4(((const float4*)x)[i]);
        }
    } else {
        int base = (b - 640) * 1024;                  // 49152 slots
        #pragma unroll
        for (int r = 0; r < 4; r++) {
            int i = base + r * 256 + t;
            float4 f;
            if (i < 16384)      f = ((const float4*)Wq)[i];
            else if (i < 32768) f = ((const float4*)Wk)[i - 16384];
            else                f = ((const float4*)Wv)[i - 32768];
            *(uint2*)(wqkvb + 4 * (size_t)i) = cvt4(f);
        }
    }
}

// ---------------------------------------------------------------------------
// K2 fused scatter + QKV MFMA GEMM (R11-proven, single-shot).
// ---------------------------------------------------------------------------
__global__ __launch_bounds__(256) void scatter_qkv_kernel(
    const int* __restrict__ e, int E, int N,
    unsigned* __restrict__ mask, const unsigned* __restrict__ orbuf,
    const u16* __restrict__ xb, const u16* __restrict__ wqkvb,
    const float* __restrict__ bq, const float* __restrict__ bk,
    const float* __restrict__ bv,
    u16* __restrict__ q, u16* __restrict__ k, u16* __restrict__ v)
{
    int t = threadIdx.x;

    if (blockIdx.x < 128) {
        unsigned oo = orbuf[t & 63];
        #pragma unroll
        for (int o = 32; o > 0; o >>= 1) oo |= __shfl_xor(oo, o, 64);
        bool i32mode = (oo != 0);
        int nw = N >> 5;
        for (int i = blockIdx.x * 256 + t; i < E; i += 128 * 256) {
            int row, col;
            if (i32mode) { row = e[i];     col = e[E + i]; }
            else         { row = e[2 * i]; col = e[2 * E + 2 * i]; }
            if ((unsigned)row < (unsigned)N && (unsigned)col < (unsigned)N)
                atomicOr(&mask[(size_t)row * nw + (col >> 5)], 1u << (col & 31));
        }
        return;
    }

    int bid = blockIdx.x - 128;                // 0..383
    int bx = bid & 31, by = bid >> 5;          // 32 row tiles x 12 col groups
    int which = by >> 2;                       // 0=q 1=k 2=v
    int ncl = (by & 3) * 64;                   // col base within 256
    int n0f = which * 256 + ncl;               // row base in fused Wqkv
    const float* bias = (which == 0) ? bq : (which == 1) ? bk : bv;
    u16*         T    = (which == 0) ? q  : (which == 1) ? k  : v;

    int wv = t >> 6, l = t & 63, lr = l & 15, lk = l >> 4;
    int m0 = bx * 128 + wv * 32;
    f32x4 acc[2][4] = {};
    const short8* a0p = (const short8*)(xb + (size_t)(m0 + lr) * 256 + lk * 8);
    const short8* a1p = (const short8*)(xb + (size_t)(m0 + 16 + lr) * 256 + lk * 8);
    const short8* wp_ = (const short8*)(wqkvb + (size_t)(n0f + lr) * 256 + lk * 8);

    #pragma unroll
    for (int kk = 0; kk < 8; kk++) {
        short8 a0 = a0p[kk * 4];               // +32 bf16 per k-step
        short8 a1 = a1p[kk * 4];
        #pragma unroll
        for (int j = 0; j < 4; j++) {
            short8 b = wp_[(size_t)j * 16 * 32 + kk * 4];   // +16 rows = 16*256 bf16
            acc[0][j] = __builtin_amdgcn_mfma_f32_16x16x32_bf16(a0, b, acc[0][j], 0, 0, 0);
            acc[1][j] = __builtin_amdgcn_mfma_f32_16x16x32_bf16(a1, b, acc[1][j], 0, 0, 0);
        }
    }
    #pragma unroll
    for (int i2 = 0; i2 < 2; i2++)
        #pragma unroll
        for (int j = 0; j < 4; j++)
            #pragma unroll
            for (int r = 0; r < 4; r++) {
                int grow = m0 + i2 * 16 + lk * 4 + r;
                int gc   = ncl + j * 16 + lr;
                T[(size_t)grow * 256 + gc] = f2b(acc[i2][j][r] + bias[gc]);
            }
}

// ---------------------------------------------------------------------------
// K3 attn v5: R10 skeleton (1 wave/row, chunk16, 16-granule padding, 8B V
// loads) + latency hiding only:
//   (1) software-pipelined K prefetch: next chunk's 4 short8 loads issue
//       before the merge -> merge/exp/V overlap the ~400cy gather latency.
//   (2) asm lgkmcnt+memory fences REMOVED (they were scheduling walls; DS
//       ops complete in order within a wave and the compiler inserts
//       precise lgkmcnt for LDS RAW itself) -> V loads hoistable.
//   (3) fs/lsums LDS round-trips replaced by __shfl (group-uniform values);
//       ws padded [8][17] (17h%32 distinct -> conflict-free broadcast).
// Math identical to R10/R16 -> absmax unchanged.
// ---------------------------------------------------------------------------
__global__ __launch_bounds__(256) void attn_kernel(
    const unsigned* __restrict__ mask,
    const u16* __restrict__ qb, const u16* __restrict__ kb,
    const u16* __restrict__ vb, u16* __restrict__ yb, int N)
{
    __shared__ int   cols[4][MAXC];
    __shared__ float ws[4][8][17];

    int t = threadIdx.x;
    int wv = t >> 6, lane = t & 63;
    int n = blockIdx.x * 4 + wv;
    int nw = N >> 5;                        // 128

    // ---- per-wave compaction (sorted, deterministic) ----
    unsigned wa = mask[(size_t)n * nw + lane];
    unsigned wb = mask[(size_t)n * nw + 64 + lane];
    int pc = __popc(wa) + __popc(wb);
    int scan = pc;
    #pragma unroll
    for (int o = 1; o < 64; o <<= 1) {
        int pv = __shfl_up(scan, o, 64);
        if (lane >= o) scan += pv;
    }
    int cnt = __shfl(scan, 63, 64);
    if (cnt > MAXC) cnt = MAXC;
    int off = scan - pc;
    while (wa && off < MAXC) {
        int b = __ffs(wa) - 1; wa &= wa - 1;
        cols[wv][off++] = (lane << 5) + b;
    }
    while (wb && off < MAXC) {
        int b = __ffs(wb) - 1; wb &= wb - 1;
        cols[wv][off++] = ((64 + lane) << 5) + b;
    }
    int cntp = (cnt + 15) & ~15;            // pad to x16 with self-index
    if (cntp > MAXC) cntp = MAXC;
    for (int i = cnt + lane; i < cntp; i += 64) cols[wv][i] = n;

    int h8 = lane >> 4;                 // head pair (h8, h8+4)
    int jl = lane & 15;                 // neighbor slot in chunk
    int hv = lane >> 3;                 // V-phase head
    int d0 = lane * 4;                  // V-phase dims d0..d0+3

    const short8* qpA = (const short8*)(qb + (size_t)n * 256 + h8 * 32);
    const short8* qpB = (const short8*)(qb + (size_t)n * 256 + (h8 + 4) * 32);
    short8 qA0 = qpA[0], qA1 = qpA[1];
    short8 qB0 = qpB[0], qB1 = qpB[1];

    const float scale = 0.17677669529663687f;   // 1/sqrt(32)
    float mxA = -1e30f, mxB = -1e30f, lsA = 0.f, lsB = 0.f;
    float acc0 = 0.f, acc1 = 0.f, acc2 = 0.f, acc3 = 0.f;

    // prologue: chunk-0 K loads (cnt >= 1 guaranteed: self-loops)
    const u16* kr0 = kb + (size_t)cols[wv][jl] * 256;
    short8 ka0 = ((const short8*)(kr0 + h8 * 32))[0];
    short8 ka1 = ((const short8*)(kr0 + h8 * 32))[1];
    short8 kc0 = ((const short8*)(kr0 + (h8 + 4) * 32))[0];
    short8 kc1 = ((const short8*)(kr0 + (h8 + 4) * 32))[1];

    for (int c0 = 0; c0 < cntp; c0 += 16) {
        bool valid = (c0 + jl) < cnt;
        // --- dots from current K registers ---
        float sa = 0.f, sb = 0.f;
        #pragma unroll
        for (int e2 = 0; e2 < 8; e2++) {
            sa = fmaf(b2f((u16)ka0[e2]), b2f((u16)qA0[e2]), sa);
            sa = fmaf(b2f((u16)ka1[e2]), b2f((u16)qA1[e2]), sa);
            sb = fmaf(b2f((u16)kc0[e2]), b2f((u16)qB0[e2]), sb);
            sb = fmaf(b2f((u16)kc1[e2]), b2f((u16)qB1[e2]), sb);
        }
        // --- prefetch next chunk's K (overlaps merge + V below) ---
        short8 na0 = ka0, na1 = ka1, nc0 = kc0, nc1 = kc1;
        if (c0 + 16 < cntp) {
            const u16* krn = kb + (size_t)cols[wv][c0 + 16 + jl] * 256;
            na0 = ((const short8*)(krn + h8 * 32))[0];
            na1 = ((const short8*)(krn + h8 * 32))[1];
            nc0 = ((const short8*)(krn + (h8 + 4) * 32))[0];
            nc1 = ((const short8*)(krn + (h8 + 4) * 32))[1];
        }

        float s0 = valid ? sa * scale : -1e30f;
        float s1 = valid ? sb * scale : -1e30f;

        // --- online softmax merge (width-16 groups) ---
        float cm0 = s0, cm1 = s1;
        #pragma unroll
        for (int o = 8; o > 0; o >>= 1) {
            cm0 = fmaxf(cm0, __shfl_xor(cm0, o, 16));
            cm1 = fmaxf(cm1, __shfl_xor(cm1, o, 16));
        }
        float mnA = fmaxf(mxA, cm0), mnB = fmaxf(mxB, cm1);
        float fA = __expf(mxA - mnA), fB = __expf(mxB - mnB);
        float w0 = valid ? __expf(s0 - mnA) : 0.f;
        float w1 = valid ? __expf(s1 - mnB) : 0.f;
        float t0 = w0, t1 = w1;
        #pragma unroll
        for (int o = 8; o > 0; o >>= 1) {
            t0 += __shfl_xor(t0, o, 16);
            t1 += __shfl_xor(t1, o, 16);
        }
        lsA = lsA * fA + t0;  lsB = lsB * fB + t1;
        mxA = mnA;            mxB = mnB;

        ws[wv][h8][jl]     = w0;
        ws[wv][h8 + 4][jl] = w1;

        // fv via shfl (group-uniform after cascade; no LDS round trip)
        float fa_s = __shfl(fA, (hv & 3) << 4, 64);
        float fb_s = __shfl(fB, (hv & 3) << 4, 64);
        float fv = (hv < 4) ? fa_s : fb_s;
        acc0 *= fv; acc1 *= fv; acc2 *= fv; acc3 *= fv;

        // --- V accumulation: 16 coalesced 512B row reads ---
        #pragma unroll
        for (int jj = 0; jj < 16; jj++) {
            float wj = ws[wv][hv][jj];
            uint2 raw = *(const uint2*)(vb + (size_t)cols[wv][c0 + jj] * 256 + d0);
            acc0 = fmaf(wj, b2f((u16)(raw.x & 0xffff)), acc0);
            acc1 = fmaf(wj, b2f((u16)(raw.x >> 16)),    acc1);
            acc2 = fmaf(wj, b2f((u16)(raw.y & 0xffff)), acc2);
            acc3 = fmaf(wj, b2f((u16)(raw.y >> 16)),    acc3);
        }
        ka0 = na0; ka1 = na1; kc0 = nc0; kc1 = nc1;
    }

    float la_s = __shfl(lsA, (hv & 3) << 4, 64);
    float lb_s = __shfl(lsB, (hv & 3) << 4, 64);
    float ls = (hv < 4) ? la_s : lb_s;
    uint2 ov;
    ov.x = (unsigned)f2b(acc0 / ls) | ((unsigned)f2b(acc1 / ls) << 16);
    ov.y = (unsigned)f2b(acc2 / ls) | ((unsigned)f2b(acc3 / ls) << 16);
    *(uint2*)(yb + (size_t)n * 256 + d0) = ov;
}

// ---------------------------------------------------------------------------
// K4 final MFMA GEMM: out = [xb | y] @ Wp^T + bp, K=512, fp32 out
// (R11-proven, single-shot).
// ---------------------------------------------------------------------------
__global__ __launch_bounds__(256) void final_kernel(
    const u16* __restrict__ xb, const u16* __restrict__ yb,
    const u16* __restrict__ wpb, const float* __restrict__ bp,
    float* __restrict__ out)
{
    int t = threadIdx.x;
    int wv = t >> 6, l = t & 63, lr = l & 15, lk = l >> 4;
    int m0 = blockIdx.x * 64 + wv * 16;
    int n0 = blockIdx.y * 64;

    f32x4 acc[4] = {};
    const short8* axp = (const short8*)(xb + (size_t)(m0 + lr) * 256 + lk * 8);
    const short8* ayp = (const short8*)(yb + (size_t)(m0 + lr) * 256 + lk * 8);
    const short8* wp_ = (const short8*)(wpb + (size_t)(n0 + lr) * 512 + lk * 8);

    #pragma unroll
    for (int kk = 0; kk < 16; kk++) {
        short8 a = (kk < 8) ? axp[kk * 4] : ayp[(kk - 8) * 4];
        #pragma unroll
        for (int j = 0; j < 4; j++) {
            short8 b = wp_[(size_t)j * 16 * 64 + kk * 4];   // +16 rows = 16*512 bf16
            acc[j] = __builtin_amdgcn_mfma_f32_16x16x32_bf16(a, b, acc[j], 0, 0, 0);
        }
    }
    #pragma unroll
    for (int j = 0; j < 4; j++)
        #pragma unroll
        for (int r = 0; r < 4; r++) {
            int grow = m0 + lk * 4 + r;
            int gc   = n0 + j * 16 + lr;
            out[(size_t)grow * 256 + gc] = acc[j][r] + bp[gc];
        }
}

// ---------------------------------------------------------------------------
extern "C" void kernel_launch(void* const* d_in, const int* in_sizes, int n_in,
                              void* d_out, int out_size, void* d_ws, size_t ws_size,
                              hipStream_t stream) {
    const float* x  = (const float*)d_in[0];
    const int*   ei = (const int*)d_in[1];
    const float* Wq = (const float*)d_in[2];
    const float* bq = (const float*)d_in[3];
    const float* Wk = (const float*)d_in[4];
    const float* bk = (const float*)d_in[5];
    const float* Wv = (const float*)d_in[6];
    const float* bv = (const float*)d_in[7];
    const float* Wp = (const float*)d_in[8];
    const float* bp = (const float*)d_in[9];
    float* out = (float*)d_out;

    const int D = 256;
    int N = in_sizes[0] / D;       // 4096
    int E = in_sizes[1] / 2;       // 135168

    size_t maskB = (size_t)N * (N >> 5) * sizeof(unsigned);   // 2 MB
    char* ws = (char*)d_ws;
    unsigned* mask  = (unsigned*)ws;
    unsigned* orbuf = (unsigned*)(ws + maskB);                // 64 words
    u16* qbb   = (u16*)(ws + maskB + 1024);
    u16* kbb   = qbb + (size_t)N * D;
    u16* vbb   = kbb + (size_t)N * D;
    u16* ybb   = vbb + (size_t)N * D;
    u16* xbb   = ybb + (size_t)N * D;
    u16* wpb   = xbb + (size_t)N * D;                         // 131072 bf16
    u16* wqkvb = wpb + 131072;                                // 196608 bf16

    prep_kernel<<<688, 256, 0, stream>>>(
        ei, E, (uint4*)ws, (int)(maskB / 16), orbuf,
        Wp, wpb, x, xbb, Wq, Wk, Wv, wqkvb);

    scatter_qkv_kernel<<<512, 256, 0, stream>>>(
        ei, E, N, mask, orbuf, xbb, wqkvb, bq, bk, bv, qbb, kbb, vbb);

    attn_kernel<<<N / 4, 256, 0, stream>>>(mask, qbb, kbb, vbb, ybb, N);

    dim3 gf(N / 64, 4);
    final_kernel<<<gf, 256, 0, stream>>>(xbb, ybb, wpb, bp, out);
}